// Round 5
// baseline (496.264 us; speedup 1.0000x reference)
//
#include <hip/hip_runtime.h>

#define D 64

__device__ __forceinline__ float relu_f(float v) { return v > 0.f ? v : 0.f; }

// x[e][:] = fact_emb[edge_type[e]][:]
__global__ void k_gather(const int* __restrict__ et, const float* __restrict__ fe,
                         float* __restrict__ x, int E) {
    int u = blockIdx.x * blockDim.x + threadIdx.x;
    if (u >= E * 16) return;
    int e = u >> 4, q = u & 15;
    float4 v = reinterpret_cast<const float4*>(fe + (size_t)et[e] * D)[q];
    reinterpret_cast<float4*>(x + (size_t)e * D)[q] = v;
}

// ---------------- CSR build: histogram + fused scan + permute ----------------

__global__ void k_hist(const int* __restrict__ ac, int* __restrict__ cnt, int T) {
    int t = blockIdx.x * blockDim.x + threadIdx.x;
    if (t < T) atomicAdd(&cnt[ac[t]], 1);
}

// single-block exclusive scan of cnt[0..E) -> startArr, cursor
__global__ __launch_bounds__(1024) void k_scan_one(const int* __restrict__ cnt,
        int* __restrict__ startArr, int* __restrict__ cursor, int E) {
    __shared__ int ls[1024];
    const int tid = threadIdx.x;
    const int chunk = (E + 1023) / 1024;
    const int lo = tid * chunk;
    const int hi = (lo + chunk < E) ? lo + chunk : E;
    int sum = 0;
    for (int i = lo; i < hi; ++i) sum += cnt[i];
    ls[tid] = sum;
    __syncthreads();
    for (int off = 1; off < 1024; off <<= 1) {
        int v = (tid >= off) ? ls[tid - off] : 0;
        __syncthreads();
        ls[tid] += v;
        __syncthreads();
    }
    int run = ls[tid] - sum;   // exclusive prefix of this chunk
    for (int i = lo; i < hi; ++i) {
        startArr[i] = run;
        cursor[i] = run;
        run += cnt[i];
    }
}

__global__ void k_permute(const int* __restrict__ ab, const int* __restrict__ bc,
                          const int* __restrict__ ac, int* __restrict__ cursor,
                          int2* __restrict__ tri, int T) {
    int t = blockIdx.x * blockDim.x + threadIdx.x;
    if (t >= T) return;
    int pos = atomicAdd(&cursor[ac[t]], 1);
    tri[pos] = make_int2(ab[t], bc[t]);
}

// ---------------- fused message-gather + linear + relu ----------------
// one wave per edge (grid-strided): acc[lane] = sum_t xin[ab][lane]*xin[bc][lane]
// then xout[e][lane] = relu( sum_k readlane(acc,k) * W[k][lane] + b[lane] )
// inner loop unrolled x4: 4 uniform index loads, then 8 independent row loads.
__global__ __launch_bounds__(256) void k_msg_linear(const int* __restrict__ startArr,
        const int* __restrict__ cnt, const int2* __restrict__ tri,
        const float* __restrict__ xin, const float* __restrict__ W,
        const float* __restrict__ b, float* __restrict__ xout, int E, int nwaves) {
    const int lane = threadIdx.x & 63;
    const int wid = (blockIdx.x * blockDim.x + threadIdx.x) >> 6;

    float w[D];
    #pragma unroll
    for (int k = 0; k < D; ++k) w[k] = W[k * D + lane];
    const float bias = b[lane];

    for (int e = wid; e < E; e += nwaves) {
        int s = startArr[e], c = cnt[e];
        float acc = 0.f;
        int i = 0;
        for (; i + 3 < c; i += 4) {
            int2 p0 = tri[s + i + 0];
            int2 p1 = tri[s + i + 1];
            int2 p2 = tri[s + i + 2];
            int2 p3 = tri[s + i + 3];
            float a0 = xin[(size_t)p0.x * D + lane];
            float g0 = xin[(size_t)p0.y * D + lane];
            float a1 = xin[(size_t)p1.x * D + lane];
            float g1 = xin[(size_t)p1.y * D + lane];
            float a2 = xin[(size_t)p2.x * D + lane];
            float g2 = xin[(size_t)p2.y * D + lane];
            float a3 = xin[(size_t)p3.x * D + lane];
            float g3 = xin[(size_t)p3.y * D + lane];
            acc += a0 * g0;
            acc += a1 * g1;
            acc += a2 * g2;
            acc += a3 * g3;
        }
        for (; i < c; ++i) {
            int2 p = tri[s + i];
            acc += xin[(size_t)p.x * D + lane] * xin[(size_t)p.y * D + lane];
        }
        float o0 = bias, o1 = 0.f;
        int ai = __builtin_bit_cast(int, acc);
        #pragma unroll
        for (int k = 0; k < D; k += 2) {
            o0 += __builtin_bit_cast(float, __builtin_amdgcn_readlane(ai, k)) * w[k];
            o1 += __builtin_bit_cast(float, __builtin_amdgcn_readlane(ai, k + 1)) * w[k + 1];
        }
        xout[(size_t)e * D + lane] = relu_f(o0 + o1);
    }
}

// ---------------- final MLP ----------------
// out[e] = relu(concat(x[e], fe[et[e]]) @ W1 + b1) @ W2 + b2
// 1024 threads, 128 rows/block; W1 staged once (64KB) + fT[128][129] (66KB);
// 2 barriers total; compute loop identical in structure to the proven
// non-spilling round-4 loop (scalar float4 + init-list locals only).
#define MPAD 129
__global__ __launch_bounds__(1024) void k_mlp(const float* __restrict__ x,
        const int* __restrict__ et, const float* __restrict__ fe,
        const float* __restrict__ W1, const float* __restrict__ b1,
        const float* __restrict__ W2, const float* __restrict__ b2,
        float* __restrict__ out, int E) {
    __shared__ float Wl[128 * 128];     // 64 KB, all of W1
    __shared__ float fT[128 * MPAD];    // 66 KB, fT[k][r], 128 rows
    __shared__ float b1l[128];
    __shared__ float W2l[128];
    const int tid = threadIdx.x;
    const int row0 = blockIdx.x * 128;

    if (tid < 128) { b1l[tid] = b1[tid]; W2l[tid] = W2[tid]; }

    // stage all of W1
    for (int i = tid; i < 4096; i += 1024)
        reinterpret_cast<float4*>(Wl)[i] = reinterpret_cast<const float4*>(W1)[i];

    // stage features transposed: k<64 from x, k>=64 from fe[et[row]]
    for (int i = tid; i < 4096; i += 1024) {
        int r = i >> 5, q = i & 31;
        int row = row0 + r;
        float4 v = make_float4(0.f, 0.f, 0.f, 0.f);
        if (row < E) {
            if (q < 16)
                v = reinterpret_cast<const float4*>(x + (size_t)row * D)[q];
            else
                v = reinterpret_cast<const float4*>(fe + (size_t)et[row] * D)[q - 16];
        }
        int kb = q * 4;
        fT[(kb + 0) * MPAD + r] = v.x;
        fT[(kb + 1) * MPAD + r] = v.y;
        fT[(kb + 2) * MPAD + r] = v.z;
        fT[(kb + 3) * MPAD + r] = v.w;
    }
    __syncthreads();

    const int jt = tid & 31;
    const int j0 = jt * 4;
    const int r0 = (tid >> 5) * 4;
    float acc[4][4];
    #pragma unroll
    for (int i = 0; i < 4; ++i)
        #pragma unroll
        for (int j = 0; j < 4; ++j) acc[i][j] = 0.f;

    #pragma unroll 8
    for (int k = 0; k < 128; ++k) {
        float4 f = *reinterpret_cast<const float4*>(&fT[k * MPAD + r0]);
        float4 w = *reinterpret_cast<const float4*>(&Wl[k * 128 + j0]);
        float fa[4] = {f.x, f.y, f.z, f.w};
        float wa[4] = {w.x, w.y, w.z, w.w};
        #pragma unroll
        for (int i = 0; i < 4; ++i)
            #pragma unroll
            for (int j = 0; j < 4; ++j) acc[i][j] += fa[i] * wa[j];
    }

    float4 bv = *reinterpret_cast<const float4*>(&b1l[j0]);
    float4 w2 = *reinterpret_cast<const float4*>(&W2l[j0]);
    float bias2 = b2[0];
    #pragma unroll
    for (int i = 0; i < 4; ++i) {
        float h0 = relu_f(acc[i][0] + bv.x);
        float h1 = relu_f(acc[i][1] + bv.y);
        float h2 = relu_f(acc[i][2] + bv.z);
        float h3 = relu_f(acc[i][3] + bv.w);
        float p = h0 * w2.x + h1 * w2.y + h2 * w2.z + h3 * w2.w;
        #pragma unroll
        for (int m = 1; m < 32; m <<= 1) p += __shfl_xor(p, m, 64);
        if (jt == 0) {
            int row = row0 + r0 + i;
            if (row < E) out[row] = p + bias2;
        }
    }
}

extern "C" void kernel_launch(void* const* d_in, const int* in_sizes, int n_in,
                              void* d_out, int out_size, void* d_ws, size_t ws_size,
                              hipStream_t stream) {
    const int*   edge_type = (const int*)d_in[0];
    const int*   ab        = (const int*)d_in[1];
    const int*   bc        = (const int*)d_in[2];
    const int*   ac        = (const int*)d_in[3];
    const float* fe        = (const float*)d_in[4];
    const float* W1        = (const float*)d_in[5];
    const float* b1        = (const float*)d_in[6];
    const float* W2        = (const float*)d_in[7];
    const float* b2        = (const float*)d_in[8];
    const float* mW1       = (const float*)d_in[9];
    const float* mb1       = (const float*)d_in[10];
    const float* mW2       = (const float*)d_in[11];
    const float* mb2       = (const float*)d_in[12];

    const int E = in_sizes[0];
    const int T = in_sizes[1];
    float* out = (float*)d_out;

    // workspace layout
    char* p = (char*)d_ws;
    float* xa   = (float*)p;   p += (size_t)E * D * sizeof(float);
    float* xb   = (float*)p;   p += (size_t)E * D * sizeof(float);
    int* cnt    = (int*)p;     p += (size_t)E * sizeof(int);
    int* startA = (int*)p;     p += (size_t)E * sizeof(int);
    int* cursor = (int*)p;     p += (size_t)E * sizeof(int);
    int2* tri   = (int2*)p;    p += (size_t)T * sizeof(int2);

    // CSR of triangles keyed by ac (reused by both layers)
    hipMemsetAsync(cnt, 0, (size_t)E * sizeof(int), stream);
    k_hist<<<(T + 255) / 256, 256, 0, stream>>>(ac, cnt, T);
    k_scan_one<<<1, 1024, 0, stream>>>(cnt, startA, cursor, E);
    k_permute<<<(T + 255) / 256, 256, 0, stream>>>(ab, bc, ac, cursor, tri, T);

    k_gather<<<(E * 16 + 255) / 256, 256, 0, stream>>>(edge_type, fe, xa, E);

    const int MSG_BLOCKS = 2560;
    const int nwaves = MSG_BLOCKS * 256 / 64;
    // layer 1: xa -> xb ; layer 2: xb -> xa
    k_msg_linear<<<MSG_BLOCKS, 256, 0, stream>>>(startA, cnt, tri, xa, W1, b1, xb, E, nwaves);
    k_msg_linear<<<MSG_BLOCKS, 256, 0, stream>>>(startA, cnt, tri, xb, W2, b2, xa, E, nwaves);

    k_mlp<<<(E + 127) / 128, 1024, 0, stream>>>(xa, edge_type, fe, mW1, mb1, mW2, mb2, out, E);
}

// Round 6
// 274.447 us; speedup vs baseline: 1.8082x; 1.8082x over previous
//
#include <hip/hip_runtime.h>

#define D 64

__device__ __forceinline__ float relu_f(float v) { return v > 0.f ? v : 0.f; }

// x[e][:] = fact_emb[edge_type[e]][:]
__global__ void k_gather(const int* __restrict__ et, const float* __restrict__ fe,
                         float* __restrict__ x, int E) {
    int u = blockIdx.x * blockDim.x + threadIdx.x;
    if (u >= E * 16) return;
    int e = u >> 4, q = u & 15;
    float4 v = reinterpret_cast<const float4*>(fe + (size_t)et[e] * D)[q];
    reinterpret_cast<float4*>(x + (size_t)e * D)[q] = v;
}

// ---------------- CSR build: histogram + 3-pass scan + permute ----------------

__global__ void k_hist(const int* __restrict__ ac, int* __restrict__ cnt, int T) {
    int t = blockIdx.x * blockDim.x + threadIdx.x;
    if (t < T) atomicAdd(&cnt[ac[t]], 1);
}

__global__ __launch_bounds__(256) void k_scanA(const int* __restrict__ cnt,
        int* __restrict__ localExcl, int* __restrict__ blockSums, int E) {
    __shared__ int ls[256];
    const int tid = threadIdx.x;
    int base = blockIdx.x * 1024 + tid * 4;
    int a0 = 0, a1 = 0, a2 = 0, a3 = 0;
    if (base + 3 < E) {
        int4 v = *reinterpret_cast<const int4*>(cnt + base);
        a0 = v.x; a1 = v.y; a2 = v.z; a3 = v.w;
    } else {
        if (base + 0 < E) a0 = cnt[base + 0];
        if (base + 1 < E) a1 = cnt[base + 1];
        if (base + 2 < E) a2 = cnt[base + 2];
        if (base + 3 < E) a3 = cnt[base + 3];
    }
    int tsum = a0 + a1 + a2 + a3;
    ls[tid] = tsum;
    __syncthreads();
    for (int off = 1; off < 256; off <<= 1) {
        int v = (tid >= off) ? ls[tid - off] : 0;
        __syncthreads();
        ls[tid] += v;
        __syncthreads();
    }
    int excl = ls[tid] - tsum;
    if (tid == 255) blockSums[blockIdx.x] = ls[255];
    if (base + 3 < E) {
        int4 o = make_int4(excl, excl + a0, excl + a0 + a1, excl + a0 + a1 + a2);
        *reinterpret_cast<int4*>(localExcl + base) = o;
    } else {
        int run = excl;
        if (base + 0 < E) { localExcl[base + 0] = run; run += a0; }
        if (base + 1 < E) { localExcl[base + 1] = run; run += a1; }
        if (base + 2 < E) { localExcl[base + 2] = run; run += a2; }
        if (base + 3 < E) { localExcl[base + 3] = run; }
    }
}

__global__ __launch_bounds__(256) void k_scanB(int* __restrict__ blockSums, int n) {
    __shared__ int ls[256];
    const int tid = threadIdx.x;
    int v = (tid < n) ? blockSums[tid] : 0;
    ls[tid] = v;
    __syncthreads();
    for (int off = 1; off < 256; off <<= 1) {
        int w = (tid >= off) ? ls[tid - off] : 0;
        __syncthreads();
        ls[tid] += w;
        __syncthreads();
    }
    if (tid < n) blockSums[tid] = ls[tid] - v;   // exclusive
}

// seg[i] = (start, count); cursor[i] = start
__global__ void k_scanC(const int* __restrict__ localExcl, const int* __restrict__ blockSums,
                        const int* __restrict__ cnt, int2* __restrict__ seg,
                        int* __restrict__ cursor, int E) {
    int i = blockIdx.x * blockDim.x + threadIdx.x;
    if (i < E) {
        int s = localExcl[i] + blockSums[i >> 10];
        seg[i] = make_int2(s, cnt[i]);
        cursor[i] = s;
    }
}

__global__ void k_permute(const int* __restrict__ ab, const int* __restrict__ bc,
                          const int* __restrict__ ac, int* __restrict__ cursor,
                          int2* __restrict__ tri, int T) {
    int t = blockIdx.x * blockDim.x + threadIdx.x;
    if (t >= T) return;
    int pos = atomicAdd(&cursor[ac[t]], 1);
    tri[pos] = make_int2(ab[t], bc[t]);
}

// ---------------- fused message-gather + linear + relu ----------------
// one wave per edge (grid-strided, seg prefetch pipelined):
//   acc[lane] = sum_t xin[ab][lane]*xin[bc][lane]
//   xout[e][lane] = relu( sum_k readlane(acc,k) * Wl[k][lane] + b[lane] )
// W + b staged in LDS (16.3 KB) so VGPR stays low -> 8 waves/SIMD.
__global__ __launch_bounds__(256) void k_msg_linear(const int2* __restrict__ seg,
        const int2* __restrict__ tri, const float* __restrict__ xin,
        const float* __restrict__ W, const float* __restrict__ b,
        float* __restrict__ xout, int E, int nwaves) {
    __shared__ float Wl[64 * 64];   // 16 KB
    __shared__ float bl[64];
    const int tid = threadIdx.x;
    for (int i = tid; i < 1024; i += 256)
        reinterpret_cast<float4*>(Wl)[i] = reinterpret_cast<const float4*>(W)[i];
    if (tid < 64) bl[tid] = b[tid];
    __syncthreads();

    const int lane = tid & 63;
    int e = (blockIdx.x * blockDim.x + tid) >> 6;
    if (e >= E) return;

    int2 sc = seg[e];
    while (true) {
        const int en = e + nwaves;
        int2 scn = make_int2(0, 0);
        if (en < E) scn = seg[en];          // prefetch next edge's descriptor

        const int s = sc.x, c = sc.y;
        float acc = 0.f;
        int i = 0;
        for (; i + 3 < c; i += 4) {
            int2 p0 = tri[s + i + 0];
            int2 p1 = tri[s + i + 1];
            int2 p2 = tri[s + i + 2];
            int2 p3 = tri[s + i + 3];
            float a0 = xin[(size_t)p0.x * D + lane];
            float g0 = xin[(size_t)p0.y * D + lane];
            float a1 = xin[(size_t)p1.x * D + lane];
            float g1 = xin[(size_t)p1.y * D + lane];
            float a2 = xin[(size_t)p2.x * D + lane];
            float g2 = xin[(size_t)p2.y * D + lane];
            float a3 = xin[(size_t)p3.x * D + lane];
            float g3 = xin[(size_t)p3.y * D + lane];
            acc += a0 * g0;
            acc += a1 * g1;
            acc += a2 * g2;
            acc += a3 * g3;
        }
        for (; i < c; ++i) {
            int2 p = tri[s + i];
            acc += xin[(size_t)p.x * D + lane] * xin[(size_t)p.y * D + lane];
        }

        float o0 = bl[lane], o1 = 0.f;
        int ai = __builtin_bit_cast(int, acc);
        #pragma unroll
        for (int k = 0; k < D; k += 2) {
            o0 += __builtin_bit_cast(float, __builtin_amdgcn_readlane(ai, k)) * Wl[k * 64 + lane];
            o1 += __builtin_bit_cast(float, __builtin_amdgcn_readlane(ai, k + 1)) * Wl[(k + 1) * 64 + lane];
        }
        xout[(size_t)e * D + lane] = relu_f(o0 + o1);

        if (en >= E) break;
        e = en; sc = scn;
    }
}

// ---------------- final MLP ----------------
// out[e] = relu(concat(x[e], fe[et[e]]) @ W1 + b1) @ W2 + b2
// 1024 threads, 128 rows/block; W1 staged once (64KB) + fT[128][129] (66KB).
#define MPAD 129
__global__ __launch_bounds__(1024) void k_mlp(const float* __restrict__ x,
        const int* __restrict__ et, const float* __restrict__ fe,
        const float* __restrict__ W1, const float* __restrict__ b1,
        const float* __restrict__ W2, const float* __restrict__ b2,
        float* __restrict__ out, int E) {
    __shared__ float Wl[128 * 128];     // 64 KB, all of W1
    __shared__ float fT[128 * MPAD];    // 66 KB, fT[k][r], 128 rows
    __shared__ float b1l[128];
    __shared__ float W2l[128];
    const int tid = threadIdx.x;
    const int row0 = blockIdx.x * 128;

    if (tid < 128) { b1l[tid] = b1[tid]; W2l[tid] = W2[tid]; }

    for (int i = tid; i < 4096; i += 1024)
        reinterpret_cast<float4*>(Wl)[i] = reinterpret_cast<const float4*>(W1)[i];

    for (int i = tid; i < 4096; i += 1024) {
        int r = i >> 5, q = i & 31;
        int row = row0 + r;
        float4 v = make_float4(0.f, 0.f, 0.f, 0.f);
        if (row < E) {
            if (q < 16)
                v = reinterpret_cast<const float4*>(x + (size_t)row * D)[q];
            else
                v = reinterpret_cast<const float4*>(fe + (size_t)et[row] * D)[q - 16];
        }
        int kb = q * 4;
        fT[(kb + 0) * MPAD + r] = v.x;
        fT[(kb + 1) * MPAD + r] = v.y;
        fT[(kb + 2) * MPAD + r] = v.z;
        fT[(kb + 3) * MPAD + r] = v.w;
    }
    __syncthreads();

    const int jt = tid & 31;
    const int j0 = jt * 4;
    const int r0 = (tid >> 5) * 4;
    float acc[4][4];
    #pragma unroll
    for (int i = 0; i < 4; ++i)
        #pragma unroll
        for (int j = 0; j < 4; ++j) acc[i][j] = 0.f;

    #pragma unroll 8
    for (int k = 0; k < 128; ++k) {
        float4 f = *reinterpret_cast<const float4*>(&fT[k * MPAD + r0]);
        float4 w = *reinterpret_cast<const float4*>(&Wl[k * 128 + j0]);
        float fa[4] = {f.x, f.y, f.z, f.w};
        float wa[4] = {w.x, w.y, w.z, w.w};
        #pragma unroll
        for (int i = 0; i < 4; ++i)
            #pragma unroll
            for (int j = 0; j < 4; ++j) acc[i][j] += fa[i] * wa[j];
    }

    float4 bv = *reinterpret_cast<const float4*>(&b1l[j0]);
    float4 w2 = *reinterpret_cast<const float4*>(&W2l[j0]);
    float bias2 = b2[0];
    #pragma unroll
    for (int i = 0; i < 4; ++i) {
        float h0 = relu_f(acc[i][0] + bv.x);
        float h1 = relu_f(acc[i][1] + bv.y);
        float h2 = relu_f(acc[i][2] + bv.z);
        float h3 = relu_f(acc[i][3] + bv.w);
        float p = h0 * w2.x + h1 * w2.y + h2 * w2.z + h3 * w2.w;
        #pragma unroll
        for (int m = 1; m < 32; m <<= 1) p += __shfl_xor(p, m, 64);
        if (jt == 0) {
            int row = row0 + r0 + i;
            if (row < E) out[row] = p + bias2;
        }
    }
}

extern "C" void kernel_launch(void* const* d_in, const int* in_sizes, int n_in,
                              void* d_out, int out_size, void* d_ws, size_t ws_size,
                              hipStream_t stream) {
    const int*   edge_type = (const int*)d_in[0];
    const int*   ab        = (const int*)d_in[1];
    const int*   bc        = (const int*)d_in[2];
    const int*   ac        = (const int*)d_in[3];
    const float* fe        = (const float*)d_in[4];
    const float* W1        = (const float*)d_in[5];
    const float* b1        = (const float*)d_in[6];
    const float* W2        = (const float*)d_in[7];
    const float* b2        = (const float*)d_in[8];
    const float* mW1       = (const float*)d_in[9];
    const float* mb1       = (const float*)d_in[10];
    const float* mW2       = (const float*)d_in[11];
    const float* mb2       = (const float*)d_in[12];

    const int E = in_sizes[0];
    const int T = in_sizes[1];
    float* out = (float*)d_out;

    // workspace layout
    char* p = (char*)d_ws;
    float* xa   = (float*)p;   p += (size_t)E * D * sizeof(float);
    float* xb   = (float*)p;   p += (size_t)E * D * sizeof(float);
    int* cnt    = (int*)p;     p += (size_t)E * sizeof(int);
    int* lexcl  = (int*)p;     p += (size_t)E * sizeof(int);
    int* cursor = (int*)p;     p += (size_t)E * sizeof(int);
    int* bsums  = (int*)p;     p += 256 * sizeof(int);
    int2* seg   = (int2*)p;    p += (size_t)E * sizeof(int2);
    int2* tri   = (int2*)p;    p += (size_t)T * sizeof(int2);

    const int nblkA = (E + 1023) / 1024;

    // CSR of triangles keyed by ac (reused by both layers)
    hipMemsetAsync(cnt, 0, (size_t)E * sizeof(int), stream);
    k_hist<<<(T + 255) / 256, 256, 0, stream>>>(ac, cnt, T);
    k_scanA<<<nblkA, 256, 0, stream>>>(cnt, lexcl, bsums, E);
    k_scanB<<<1, 256, 0, stream>>>(bsums, nblkA);
    k_scanC<<<(E + 255) / 256, 256, 0, stream>>>(lexcl, bsums, cnt, seg, cursor, E);
    k_permute<<<(T + 255) / 256, 256, 0, stream>>>(ab, bc, ac, cursor, tri, T);

    k_gather<<<(E * 16 + 255) / 256, 256, 0, stream>>>(edge_type, fe, xa, E);

    const int MSG_BLOCKS = 2048;
    const int nwaves = MSG_BLOCKS * 256 / 64;
    // layer 1: xa -> xb ; layer 2: xb -> xa
    k_msg_linear<<<MSG_BLOCKS, 256, 0, stream>>>(seg, tri, xa, W1, b1, xb, E, nwaves);
    k_msg_linear<<<MSG_BLOCKS, 256, 0, stream>>>(seg, tri, xb, W2, b2, xa, E, nwaves);

    k_mlp<<<(E + 127) / 128, 1024, 0, stream>>>(xa, edge_type, fe, mW1, mb1, mW2, mb2, out, E);
}

// Round 7
// 248.072 us; speedup vs baseline: 2.0005x; 1.1063x over previous
//
#include <hip/hip_runtime.h>

#define D 64

__device__ __forceinline__ float relu_f(float v) { return v > 0.f ? v : 0.f; }

// x[e][:] = fact_emb[edge_type[e]][:]
__global__ void k_gather(const int* __restrict__ et, const float* __restrict__ fe,
                         float* __restrict__ x, int E) {
    int u = blockIdx.x * blockDim.x + threadIdx.x;
    if (u >= E * 16) return;
    int e = u >> 4, q = u & 15;
    float4 v = reinterpret_cast<const float4*>(fe + (size_t)et[e] * D)[q];
    reinterpret_cast<float4*>(x + (size_t)e * D)[q] = v;
}

// ---------------- CSR build: histogram + 3-pass scan + permute ----------------

__global__ void k_hist(const int* __restrict__ ac, int* __restrict__ cnt, int T) {
    int t = blockIdx.x * blockDim.x + threadIdx.x;
    if (t < T) atomicAdd(&cnt[ac[t]], 1);
}

__global__ __launch_bounds__(256) void k_scanA(const int* __restrict__ cnt,
        int* __restrict__ localExcl, int* __restrict__ blockSums, int E) {
    __shared__ int ls[256];
    const int tid = threadIdx.x;
    int base = blockIdx.x * 1024 + tid * 4;
    int a0 = 0, a1 = 0, a2 = 0, a3 = 0;
    if (base + 3 < E) {
        int4 v = *reinterpret_cast<const int4*>(cnt + base);
        a0 = v.x; a1 = v.y; a2 = v.z; a3 = v.w;
    } else {
        if (base + 0 < E) a0 = cnt[base + 0];
        if (base + 1 < E) a1 = cnt[base + 1];
        if (base + 2 < E) a2 = cnt[base + 2];
        if (base + 3 < E) a3 = cnt[base + 3];
    }
    int tsum = a0 + a1 + a2 + a3;
    ls[tid] = tsum;
    __syncthreads();
    for (int off = 1; off < 256; off <<= 1) {
        int v = (tid >= off) ? ls[tid - off] : 0;
        __syncthreads();
        ls[tid] += v;
        __syncthreads();
    }
    int excl = ls[tid] - tsum;
    if (tid == 255) blockSums[blockIdx.x] = ls[255];
    if (base + 3 < E) {
        int4 o = make_int4(excl, excl + a0, excl + a0 + a1, excl + a0 + a1 + a2);
        *reinterpret_cast<int4*>(localExcl + base) = o;
    } else {
        int run = excl;
        if (base + 0 < E) { localExcl[base + 0] = run; run += a0; }
        if (base + 1 < E) { localExcl[base + 1] = run; run += a1; }
        if (base + 2 < E) { localExcl[base + 2] = run; run += a2; }
        if (base + 3 < E) { localExcl[base + 3] = run; }
    }
}

__global__ __launch_bounds__(256) void k_scanB(int* __restrict__ blockSums, int n) {
    __shared__ int ls[256];
    const int tid = threadIdx.x;
    int v = (tid < n) ? blockSums[tid] : 0;
    ls[tid] = v;
    __syncthreads();
    for (int off = 1; off < 256; off <<= 1) {
        int w = (tid >= off) ? ls[tid - off] : 0;
        __syncthreads();
        ls[tid] += w;
        __syncthreads();
    }
    if (tid < n) blockSums[tid] = ls[tid] - v;   // exclusive
}

// seg[i] = (start, count); cursor[i] = start
__global__ void k_scanC(const int* __restrict__ localExcl, const int* __restrict__ blockSums,
                        const int* __restrict__ cnt, int2* __restrict__ seg,
                        int* __restrict__ cursor, int E) {
    int i = blockIdx.x * blockDim.x + threadIdx.x;
    if (i < E) {
        int s = localExcl[i] + blockSums[i >> 10];
        seg[i] = make_int2(s, cnt[i]);
        cursor[i] = s;
    }
}

__global__ void k_permute(const int* __restrict__ ab, const int* __restrict__ bc,
                          const int* __restrict__ ac, int* __restrict__ cursor,
                          int2* __restrict__ tri, int T) {
    int t = blockIdx.x * blockDim.x + threadIdx.x;
    if (t >= T) return;
    int pos = atomicAdd(&cursor[ac[t]], 1);
    tri[pos] = make_int2(ab[t], bc[t]);
}

// ---------------- message gather (no epilogue) ----------------
// wave = 4 groups of 16 lanes; group g owns edge quad*4+g; lane sub holds
// float4 of dims [4*sub..4*sub+3]. agg[e][:] = sum_t x[ab_t][:]*x[bc_t][:]
__global__ __launch_bounds__(256) void k_msg4(const int2* __restrict__ seg,
        const int2* __restrict__ tri, const float* __restrict__ xin,
        float* __restrict__ agg, int E, int nquad) {
    const int tid = threadIdx.x;
    const int lane = tid & 63;
    const int sub = lane & 15;
    const int grp = lane >> 4;
    const float4* __restrict__ x4 = reinterpret_cast<const float4*>(xin);

    for (int quad = (blockIdx.x * blockDim.x + tid) >> 6; quad * 4 < E; quad += nquad) {
        const int e = quad * 4 + grp;
        int2 sc = make_int2(0, 0);
        if (e < E) sc = seg[e];
        const int s = sc.x, c = sc.y;
        float4 acc = make_float4(0.f, 0.f, 0.f, 0.f);
        for (int i = 0; i < c; ++i) {       // divergent across groups: exec-masked
            int2 p = tri[s + i];
            float4 va = x4[(size_t)p.x * 16 + sub];
            float4 vb = x4[(size_t)p.y * 16 + sub];
            acc.x += va.x * vb.x;
            acc.y += va.y * vb.y;
            acc.z += va.z * vb.z;
            acc.w += va.w * vb.w;
        }
        if (e < E)
            reinterpret_cast<float4*>(agg + (size_t)e * D)[sub] = acc;
    }
}

// ---------------- 64x64 linear + relu (tiled, proven structure) ----------------
#define FPAD 65
__global__ __launch_bounds__(256) void k_linear(const float* __restrict__ in,
        const float* __restrict__ W, const float* __restrict__ b,
        float* __restrict__ outx, int E) {
    __shared__ float Wl[64 * 64];       // 16 KB
    __shared__ float fT[64 * FPAD];     // 16.6 KB, fT[k][r]
    const int tid = threadIdx.x;
    const int row0 = blockIdx.x * 64;

    for (int i = tid; i < 1024; i += 256)
        reinterpret_cast<float4*>(Wl)[i] = reinterpret_cast<const float4*>(W)[i];

    for (int i = tid; i < 1024; i += 256) {
        int r = i >> 4, q = i & 15;
        float4 v = make_float4(0.f, 0.f, 0.f, 0.f);
        if (row0 + r < E)
            v = reinterpret_cast<const float4*>(in + (size_t)(row0 + r) * D)[q];
        fT[(q * 4 + 0) * FPAD + r] = v.x;
        fT[(q * 4 + 1) * FPAD + r] = v.y;
        fT[(q * 4 + 2) * FPAD + r] = v.z;
        fT[(q * 4 + 3) * FPAD + r] = v.w;
    }
    __syncthreads();

    const int j0 = (tid & 15) * 4;
    const int r0 = (tid >> 4) * 4;
    float acc[4][4];
    #pragma unroll
    for (int i = 0; i < 4; ++i)
        #pragma unroll
        for (int j = 0; j < 4; ++j) acc[i][j] = 0.f;

    #pragma unroll 8
    for (int k = 0; k < 64; ++k) {
        float4 f = *reinterpret_cast<const float4*>(&fT[k * FPAD + r0]);
        float4 w = *reinterpret_cast<const float4*>(&Wl[k * 64 + j0]);
        float fa[4] = {f.x, f.y, f.z, f.w};
        float wa[4] = {w.x, w.y, w.z, w.w};
        #pragma unroll
        for (int i = 0; i < 4; ++i)
            #pragma unroll
            for (int j = 0; j < 4; ++j) acc[i][j] += fa[i] * wa[j];
    }

    float4 bv = *reinterpret_cast<const float4*>(&b[j0]);
    float ba[4] = {bv.x, bv.y, bv.z, bv.w};
    #pragma unroll
    for (int i = 0; i < 4; ++i) {
        int row = row0 + r0 + i;
        if (row < E) {
            float4 o;
            o.x = relu_f(acc[i][0] + ba[0]);
            o.y = relu_f(acc[i][1] + ba[1]);
            o.z = relu_f(acc[i][2] + ba[2]);
            o.w = relu_f(acc[i][3] + ba[3]);
            *reinterpret_cast<float4*>(outx + (size_t)row * D + j0) = o;
        }
    }
}

// ---------------- final MLP ----------------
// out[e] = relu(concat(x[e], fe[et[e]]) @ W1 + b1) @ W2 + b2
// 512 thr, 128 rows/block, 8x4 register blocking (1.5 B/FLOP LDS traffic);
// W1 + fT staged in k-halves (32 KB + 33 KB -> 2 blocks/CU).
#define MPAD 129
__global__ __launch_bounds__(512) void k_mlp(const float* __restrict__ x,
        const int* __restrict__ et, const float* __restrict__ fe,
        const float* __restrict__ W1, const float* __restrict__ b1,
        const float* __restrict__ W2, const float* __restrict__ b2,
        float* __restrict__ out, int E) {
    __shared__ float Wl[64 * 128];      // 32 KB: one k-half of W1
    __shared__ float fT[64 * MPAD];     // 33 KB: fT[k_local][r], 128 rows
    __shared__ float b1l[128];
    __shared__ float W2l[128];
    const int tid = threadIdx.x;
    const int row0 = blockIdx.x * 128;

    if (tid < 128) { b1l[tid] = b1[tid]; W2l[tid] = W2[tid]; }

    const int jt = tid & 31;
    const int j0 = jt * 4;
    const int r0 = (tid >> 5) * 8;
    float acc[8][4];
    #pragma unroll
    for (int i = 0; i < 8; ++i)
        #pragma unroll
        for (int j = 0; j < 4; ++j) acc[i][j] = 0.f;

    for (int h = 0; h < 2; ++h) {
        __syncthreads();   // h=0: order b1l/W2l; h=1: previous half's readers done
        for (int i = tid; i < 2048; i += 512)
            reinterpret_cast<float4*>(Wl)[i] =
                reinterpret_cast<const float4*>(W1 + (size_t)h * 64 * 128)[i];
        for (int i = tid; i < 2048; i += 512) {
            int r = i >> 4, q = i & 15;
            int row = row0 + r;
            float4 v = make_float4(0.f, 0.f, 0.f, 0.f);
            if (row < E) {
                if (h == 0)
                    v = reinterpret_cast<const float4*>(x + (size_t)row * D)[q];
                else
                    v = reinterpret_cast<const float4*>(fe + (size_t)et[row] * D)[q];
            }
            int kb = q * 4;
            fT[(kb + 0) * MPAD + r] = v.x;
            fT[(kb + 1) * MPAD + r] = v.y;
            fT[(kb + 2) * MPAD + r] = v.z;
            fT[(kb + 3) * MPAD + r] = v.w;
        }
        __syncthreads();

        #pragma unroll 4
        for (int k = 0; k < 64; ++k) {
            float4 fA = *reinterpret_cast<const float4*>(&fT[k * MPAD + r0]);
            float4 fB = *reinterpret_cast<const float4*>(&fT[k * MPAD + r0 + 4]);
            float4 w = *reinterpret_cast<const float4*>(&Wl[k * 128 + j0]);
            float fa[8] = {fA.x, fA.y, fA.z, fA.w, fB.x, fB.y, fB.z, fB.w};
            float wa[4] = {w.x, w.y, w.z, w.w};
            #pragma unroll
            for (int i = 0; i < 8; ++i)
                #pragma unroll
                for (int j = 0; j < 4; ++j) acc[i][j] += fa[i] * wa[j];
        }
    }

    float4 bv = *reinterpret_cast<const float4*>(&b1l[j0]);
    float4 w2 = *reinterpret_cast<const float4*>(&W2l[j0]);
    float bias2 = b2[0];
    #pragma unroll
    for (int i = 0; i < 8; ++i) {
        float h0 = relu_f(acc[i][0] + bv.x);
        float h1 = relu_f(acc[i][1] + bv.y);
        float h2 = relu_f(acc[i][2] + bv.z);
        float h3 = relu_f(acc[i][3] + bv.w);
        float p = h0 * w2.x + h1 * w2.y + h2 * w2.z + h3 * w2.w;
        #pragma unroll
        for (int m = 1; m < 32; m <<= 1) p += __shfl_xor(p, m, 64);
        if (jt == 0) {
            int row = row0 + r0 + i;
            if (row < E) out[row] = p + bias2;
        }
    }
}

extern "C" void kernel_launch(void* const* d_in, const int* in_sizes, int n_in,
                              void* d_out, int out_size, void* d_ws, size_t ws_size,
                              hipStream_t stream) {
    const int*   edge_type = (const int*)d_in[0];
    const int*   ab        = (const int*)d_in[1];
    const int*   bc        = (const int*)d_in[2];
    const int*   ac        = (const int*)d_in[3];
    const float* fe        = (const float*)d_in[4];
    const float* W1        = (const float*)d_in[5];
    const float* b1        = (const float*)d_in[6];
    const float* W2        = (const float*)d_in[7];
    const float* b2        = (const float*)d_in[8];
    const float* mW1       = (const float*)d_in[9];
    const float* mb1       = (const float*)d_in[10];
    const float* mW2       = (const float*)d_in[11];
    const float* mb2       = (const float*)d_in[12];

    const int E = in_sizes[0];
    const int T = in_sizes[1];
    float* out = (float*)d_out;

    // workspace layout
    char* p = (char*)d_ws;
    float* xa   = (float*)p;   p += (size_t)E * D * sizeof(float);
    float* xb   = (float*)p;   p += (size_t)E * D * sizeof(float);
    float* agg  = (float*)p;   p += (size_t)E * D * sizeof(float);
    int* cnt    = (int*)p;     p += (size_t)E * sizeof(int);
    int* lexcl  = (int*)p;     p += (size_t)E * sizeof(int);
    int* cursor = (int*)p;     p += (size_t)E * sizeof(int);
    int* bsums  = (int*)p;     p += 256 * sizeof(int);
    int2* seg   = (int2*)p;    p += (size_t)E * sizeof(int2);
    int2* tri   = (int2*)p;    p += (size_t)T * sizeof(int2);

    const int nblkA = (E + 1023) / 1024;

    // CSR of triangles keyed by ac (reused by both layers)
    hipMemsetAsync(cnt, 0, (size_t)E * sizeof(int), stream);
    k_hist<<<(T + 255) / 256, 256, 0, stream>>>(ac, cnt, T);
    k_scanA<<<nblkA, 256, 0, stream>>>(cnt, lexcl, bsums, E);
    k_scanB<<<1, 256, 0, stream>>>(bsums, nblkA);
    k_scanC<<<(E + 255) / 256, 256, 0, stream>>>(lexcl, bsums, cnt, seg, cursor, E);
    k_permute<<<(T + 255) / 256, 256, 0, stream>>>(ab, bc, ac, cursor, tri, T);

    k_gather<<<(E * 16 + 255) / 256, 256, 0, stream>>>(edge_type, fe, xa, E);

    const int MSG_BLOCKS = 2048;
    const int nquad = MSG_BLOCKS * 256 / 64;   // one wave per 4 edges
    // layer 1
    k_msg4<<<MSG_BLOCKS, 256, 0, stream>>>(seg, tri, xa, agg, E, nquad);
    k_linear<<<(E + 63) / 64, 256, 0, stream>>>(agg, W1, b1, xb, E);
    // layer 2
    k_msg4<<<MSG_BLOCKS, 256, 0, stream>>>(seg, tri, xb, agg, E, nquad);
    k_linear<<<(E + 63) / 64, 256, 0, stream>>>(agg, W2, b2, xa, E);

    k_mlp<<<(E + 127) / 128, 512, 0, stream>>>(xa, edge_type, fe, mW1, mb1, mW2, mb2, out, E);
}